// Round 5
// baseline (180.051 us; speedup 1.0000x reference)
//
#include <hip/hip_runtime.h>
#include <cstdint>

#define NROWS 131072
#define HD    128      // H == IN == 128
#define NDIM  512      // 4*H
#define OUTQ  16777216 // NROWS*HD

using bf16x8 = __attribute__((ext_vector_type(8))) short;
using f32x4  = __attribute__((ext_vector_type(4))) float;

#define SB() __builtin_amdgcn_sched_barrier(0)
#define BARRIER() do { asm volatile("" ::: "memory"); \
                       __builtin_amdgcn_s_barrier();  \
                       asm volatile("" ::: "memory"); } while (0)

__device__ __forceinline__ uint32_t bf16rne(float f) {
  uint32_t u = __builtin_bit_cast(uint32_t, f);
  return (u + 0x7fffu + ((u >> 16) & 1u)) >> 16;
}

__device__ __forceinline__ float tanhf_fast(float v) {
  float a = __builtin_fabsf(v);
  float e = __expf(-2.0f * a);
  float t = (1.0f - e) * __builtin_amdgcn_rcpf(1.0f + e);
  return v < 0.0f ? -t : t;
}

__device__ __forceinline__ f32x4 ldv(const float* p) {
  return *reinterpret_cast<const f32x4*>(p);
}

// Async global->LDS DMA, 16B per lane. LDS dest = uniform base + lane*16.
#define ASYNC16(g, l)                                                        \
  __builtin_amdgcn_global_load_lds(                                          \
      (const __attribute__((address_space(1))) void*)(g),                    \
      (__attribute__((address_space(3))) void*)(l), 16, 0, 0)

// Pack Wf[k][n] = W[k][n] + (k>=128 ? r[k-128][n] : 0) as bf16 fragments.
// Frag (g*8 + t)*8 + s (1 KB each): element j of lane l =
//   Wf[s*32 + (l>>4)*8 + j][gate g, col t*16 + (l&15)].
// Serves as the MFMA A-operand of Wf^T (rows = gate cols).
__global__ __launch_bounds__(256) void pack_weights(
    const float* __restrict__ W, const float* __restrict__ r,
    uint16_t* __restrict__ Bp) {
  int idx = blockIdx.x * 256 + threadIdx.x;   // 16384 frags total
  int l  = idx & 63;
  int ts = idx >> 6;
  int s  = ts & 7;
  int t  = ts >> 3;
  int ncol  = t * 16 + (l & 15);
  int kbase = s * 32 + ((l >> 4) << 3);
  uint32_t w[4];
#pragma unroll
  for (int jj = 0; jj < 4; ++jj) {
    int k0 = kbase + 2 * jj;
    float v0 = W[k0 * NDIM + ncol];
    float v1 = W[(k0 + 1) * NDIM + ncol];
    if (k0 >= 128)     v0 += r[(k0 - 128) * NDIM + ncol];
    if (k0 + 1 >= 128) v1 += r[(k0 + 1 - 128) * NDIM + ncol];
    w[jj] = bf16rne(v0) | (bf16rne(v1) << 16);
  }
  reinterpret_cast<uint4*>(Bp)[idx] = make_uint4(w[0], w[1], w[2], w[3]);
}

__global__ __launch_bounds__(256) void slstm_fused(
    const float* __restrict__ x,  const float* __restrict__ h,
    const float* __restrict__ cs, const float* __restrict__ ns,
    const float* __restrict__ ms, const float* __restrict__ bias,
    const uint16_t* __restrict__ Bp, float* __restrict__ out) {
  // 32 KB LDS, time-shared: phase 1 = x|h staging (64 x 512B, swizzled);
  // phase 2 = weight tile buffer (32 frags x 1 KB).
  __shared__ __align__(16) char smem[32768];
  const int tid  = threadIdx.x;
  const int wave = tid >> 6;
  const int lane = tid & 63;
  const int row0 = blockIdx.x * 64;
  const int l15  = lane & 15;
  const int lg   = lane >> 4;

  const int    myrow = row0 + wave * 16 + l15;
  const size_t rbase = (size_t)myrow * HD;
  const int    jb    = lg * 4;

  // 2-tile-deep c/n/m pipeline (3 SSA sets, rotated under full unroll)
  f32x4 cv0 = ldv(cs + rbase + jb);
  f32x4 nv0 = ldv(ns + rbase + jb);
  f32x4 mv0 = ldv(ms + rbase + jb);
  f32x4 cv1 = ldv(cs + rbase + jb + 16);
  f32x4 nv1 = ldv(ns + rbase + jb + 16);
  f32x4 mv1 = ldv(ms + rbase + jb + 16);
  f32x4 cv2 = {0,0,0,0}, nv2 = {0,0,0,0}, mv2 = {0,0,0,0};

  // ---- stage x (cols 0..127) then h (cols 128..255) as bf16, XOR-swizzled ----
#pragma unroll
  for (int i = 0; i < 8; ++i) {
    int e   = (i * 256 + tid) * 4;
    int rw  = e >> 7;
    int col = e & 127;
    float4 v = *reinterpret_cast<const float4*>(x + (size_t)(row0 + rw) * HD + col);
    uint32_t lo = bf16rne(v.x) | (bf16rne(v.y) << 16);
    uint32_t hi = bf16rne(v.z) | (bf16rne(v.w) << 16);
    int off = (rw * 512 + col * 2) ^ ((rw & 7) << 4);
    *reinterpret_cast<uint2*>(smem + off) = make_uint2(lo, hi);
  }
#pragma unroll
  for (int i = 0; i < 8; ++i) {
    int e   = (i * 256 + tid) * 4;
    int rw  = e >> 7;
    int col = e & 127;
    float4 v = *reinterpret_cast<const float4*>(h + (size_t)(row0 + rw) * HD + col);
    uint32_t lo = bf16rne(v.x) | (bf16rne(v.y) << 16);
    uint32_t hi = bf16rne(v.z) | (bf16rne(v.w) << 16);
    int off = (rw * 512 + 256 + col * 2) ^ ((rw & 7) << 4);
    *reinterpret_cast<uint2*>(smem + off) = make_uint2(lo, hi);
  }
  __syncthreads();

  // ---- x|h fragments (MFMA B-operand) ----
  bf16x8 a[8];
  {
    int rw   = wave * 16 + l15;
    int base = rw * 512 + (lg << 4);
    int swz  = (rw & 7) << 4;
#pragma unroll
    for (int s = 0; s < 8; ++s)
      a[s] = *reinterpret_cast<const bf16x8*>(smem + ((base + s * 64) ^ swz));
  }
  __syncthreads();   // region handoff; full drain once (clean vmcnt slate)

  const char* wBytes = (const char*)Bp;
  // DMA tile 0: wave w stages gate w, k-steps 0..7
  {
    const char* gsrc = wBytes + (((size_t)(wave * 8 + 0) * 8) << 10) + (lane << 4);
    char* ldst = smem + (wave << 13);
    SB();
#pragma unroll
    for (int k = 0; k < 8; ++k)
      ASYNC16(gsrc + (k << 10), ldst + (k << 10));
    SB();
  }
  asm volatile("s_waitcnt vmcnt(0)" ::: "memory");
  BARRIER();   // tile 0 weights visible to all waves

  // ---- 8 column tiles, fully unrolled; raw barriers + counted vmcnt ----
#pragma unroll
  for (int t = 0; t < 8; ++t) {
    // region A->B: biases (older than the upcoming DMAs) + MFMA
    const int j0 = jb + 16 * t;
    const f32x4 bI = ldv(bias + j0);
    const f32x4 bF = ldv(bias + 128 + j0);
    const f32x4 bZ = ldv(bias + 256 + j0);
    const f32x4 bO = ldv(bias + 384 + j0);

    f32x4 accI = {0.f, 0.f, 0.f, 0.f};
    f32x4 accF = {0.f, 0.f, 0.f, 0.f};
    f32x4 accZ = {0.f, 0.f, 0.f, 0.f};
    f32x4 accO = {0.f, 0.f, 0.f, 0.f};
#pragma unroll
    for (int s = 0; s < 8; ++s) {
      const int lo = lane << 4;
      bf16x8 wI = *reinterpret_cast<const bf16x8*>(smem + ((0 * 8 + s) << 10) + lo);
      bf16x8 wF = *reinterpret_cast<const bf16x8*>(smem + ((1 * 8 + s) << 10) + lo);
      bf16x8 wZ = *reinterpret_cast<const bf16x8*>(smem + ((2 * 8 + s) << 10) + lo);
      bf16x8 wO = *reinterpret_cast<const bf16x8*>(smem + ((3 * 8 + s) << 10) + lo);
      accI = __builtin_amdgcn_mfma_f32_16x16x32_bf16(wI, a[s], accI, 0, 0, 0);
      accF = __builtin_amdgcn_mfma_f32_16x16x32_bf16(wF, a[s], accF, 0, 0, 0);
      accZ = __builtin_amdgcn_mfma_f32_16x16x32_bf16(wZ, a[s], accZ, 0, 0, 0);
      accO = __builtin_amdgcn_mfma_f32_16x16x32_bf16(wO, a[s], accO, 0, 0, 0);
    }
    BARRIER();   // B: all waves done READING tile t weights (no vm drain)

    // DMA tile t+1 into the (now idle) buffer; flight hides under epilogue
    SB();
    if (t < 7) {
      const char* gsrc = wBytes + (((size_t)(wave * 8 + (t + 1)) * 8) << 10) + (lane << 4);
      char* ldst = smem + (wave << 13);
#pragma unroll
      for (int k = 0; k < 8; ++k)
        ASYNC16(gsrc + (k << 10), ldst + (k << 10));
    }
    SB();

    // epilogue: exactly 4 stores + (t<6 ? 3 loads) younger than the DMAs
    f32x4 hn, cn, nn, mn;
#pragma unroll
    for (int rr = 0; rr < 4; ++rr) {
      float i_raw = accI[rr] + bI[rr];
      float f_raw = accF[rr] + bF[rr];
      float z_raw = accZ[rr] + bZ[rr];
      float o_raw = accO[rr] + bO[rr];
      float ef  = __expf(-f_raw);
      float den = 1.0f + ef;
      float fg  = __builtin_amdgcn_rcpf(den);   // sigmoid(f_raw)
      float lgf = -__logf(den);                 // log sigmoid(f_raw)
      float mnv = fmaxf(lgf + mv0[rr], i_raw);  // m_new
      float ip  = __expf(i_raw - mnv);          // i'
      float zt  = tanhf_fast(z_raw);
      float og  = __builtin_amdgcn_rcpf(1.0f + __expf(-o_raw));
      float cnv = fg * cv0[rr] + ip * zt;       // c_new (f' == f per source)
      float nnv = fg * nv0[rr] + ip;            // n_new
      hn[rr] = og * tanhf_fast(cnv * __builtin_amdgcn_rcpf(nnv));
      cn[rr] = cnv;
      nn[rr] = nnv;
      mn[rr] = mnv;
    }
    const size_t p = rbase + jb + 16 * t;
    *reinterpret_cast<f32x4*>(out + p)            = hn;
    *reinterpret_cast<f32x4*>(out + OUTQ + p)     = cn;
    *reinterpret_cast<f32x4*>(out + 2 * OUTQ + p) = nn;
    *reinterpret_cast<f32x4*>(out + 3 * OUTQ + p) = mn;

    if (t < 6) {
      const size_t pp = rbase + jb + 16 * (t + 2);
      cv2 = ldv(cs + pp);
      nv2 = ldv(ns + pp);
      mv2 = ldv(ms + pp);
    }
    SB();

    if (t < 6) {
      // younger-than-DMA vmem = 4 stores + 3 loads -> all 8 DMAs retired
      asm volatile("s_waitcnt vmcnt(7)" ::: "memory");
      BARRIER();
    } else if (t == 6) {
      // younger-than-DMA vmem = 4 stores only
      asm volatile("s_waitcnt vmcnt(4)" ::: "memory");
      BARRIER();
    }
    // rotate c/n/m pipeline
    cv0 = cv1; nv0 = nv1; mv0 = mv1;
    cv1 = cv2; nv1 = nv2; mv1 = mv2;
  }
}

extern "C" void kernel_launch(void* const* d_in, const int* in_sizes, int n_in,
                              void* d_out, int out_size, void* d_ws, size_t ws_size,
                              hipStream_t stream) {
  const float* x = (const float*)d_in[0];
  const float* h = (const float*)d_in[1];
  const float* c = (const float*)d_in[2];
  const float* n = (const float*)d_in[3];
  const float* m = (const float*)d_in[4];
  const float* W = (const float*)d_in[5];
  const float* r = (const float*)d_in[6];
  const float* b = (const float*)d_in[7];
  uint16_t* Bp = (uint16_t*)d_ws;   // 256 KB packed bf16 weights

  pack_weights<<<64, 256, 0, stream>>>(W, r, Bp);
  slstm_fused<<<NROWS / 64, 256, 0, stream>>>(x, h, c, n, m, b, Bp, (float*)d_out);
}